// Round 3
// baseline (1553.758 us; speedup 1.0000x reference)
//
#include <hip/hip_runtime.h>
#include <hip/hip_bf16.h>

// R3: transposed MFMA (C^T = W^T @ in^T), bf16 pre-packed gather rows, bias via
// MFMA, conflict-free Z transition (ds_write_b64 / ds_read_b128), deg in prep.

typedef __attribute__((ext_vector_type(8))) short short8;
typedef __attribute__((ext_vector_type(4))) float f32x4;

#define MFMA(a, b, c) __builtin_amdgcn_mfma_f32_16x16x32_bf16(a, b, c, 0, 0, 0)

union FU { short8 v; unsigned int d[4]; unsigned short us[8]; };

__device__ __forceinline__ unsigned short f2bf(float f) {
    unsigned u = __float_as_uint(f);
    u += 0x7fffu + ((u >> 16) & 1u);   // RNE (data NaN-free)
    return (unsigned short)(u >> 16);
}
__device__ __forceinline__ unsigned int pack2(float a, float b) {
    return (unsigned int)f2bf(a) | ((unsigned int)f2bf(b) << 16);
}
__device__ __forceinline__ float tanh_fast(float xv) {
    float t = __builtin_amdgcn_exp2f(xv * 2.8853900817779268f); // 2*log2(e)
    return 1.0f - 2.0f * __builtin_amdgcn_rcpf(t + 1.0f);
}

// Build W^T A-operand fragments (byte-identical layout to a B-frag of W):
// frag(c,nt): lane holds W[k = c*32 + (lane>>4)*8 + j][n = nt*16 + (lane&15)].
// km(k): >=0 -> w[km(k)*64+n], -1 -> b[n], -2 -> 0.
template <typename KM>
__device__ void build_frags(const float* __restrict__ w, const float* __restrict__ b,
                            unsigned short* dst, int nchunks, int tid, KM km) {
    int total = nchunks * 4 * 64;
    for (int f = tid; f < total; f += 256) {
        int lv = f & 63, nt = (f >> 6) & 3, c = f >> 8;
        int n = nt * 16 + (lv & 15);
        int kb = c * 32 + ((lv >> 4) << 3);
        unsigned short* o = dst + f * 8;
        #pragma unroll
        for (int j = 0; j < 8; ++j) {
            int sk = km(kb + j);
            float v = (sk >= 0) ? w[sk * 64 + n] : (sk == -1 ? b[n] : 0.f);
            o[j] = f2bf(v);
        }
    }
}

// C^T(lane q,m16 holds h=16nt+4q+r, col m16) -> Z[c][l][8] B-frag layout, conflict-free.
#define ZSTORE(Zw, accv, bias_unused)                                            \
    _Pragma("unroll")                                                            \
    for (int nt = 0; nt < 4; ++nt) {                                             \
        int zc = nt >> 1, qp = 2 * (nt & 1) + (q >> 1), jb = 4 * (q & 1);        \
        uint2 pv;                                                                \
        pv.x = pack2(tanh_fast(accv[nt][0]), tanh_fast(accv[nt][1]));            \
        pv.y = pack2(tanh_fast(accv[nt][2]), tanh_fast(accv[nt][3]));            \
        *(uint2*)(Zw + zc * 512 + (qp * 16 + m16) * 8 + jb) = pv;                \
    }

// ---------------------------------------------------------------------------
// prep1: bf16 row tables + edge pads + degree histogram
// ---------------------------------------------------------------------------
__global__ __launch_bounds__(256) void prep1(
    const float* __restrict__ ps, const float* __restrict__ pa,
    const float* __restrict__ h, const float* __restrict__ x,
    const float* __restrict__ u,
    const int* __restrict__ s2s_dst, const float* __restrict__ s2s_dis,
    const int* __restrict__ a2s_dst, const float* __restrict__ a2s_dis,
    unsigned short* __restrict__ s_row, unsigned short* __restrict__ a_row,
    unsigned short* __restrict__ e_pad_s, unsigned short* __restrict__ e_pad_a,
    float* __restrict__ deg, int NS, int NA, int ES, int EA)
{
    int R0 = NS * 80, R1 = R0 + NA * 16, R2 = R1 + ES, R3 = R2 + EA;
    for (int i = blockIdx.x * 256 + threadIdx.x; i < R3; i += gridDim.x * 256) {
        if (i < R0) {
            int n = i / 80, k = i - n * 80;
            float v = (k < 2) ? ps[n * 2 + k] : (k < 10) ? x[n * 8 + k - 2]
                    : (k < 74) ? h[n * 64 + k - 10] : 0.f;
            s_row[i] = f2bf(v);
        } else if (i < R1) {
            int j = i - R0; int a = j / 16, k = j - a * 16;
            float v = (k < 2) ? pa[a * 2 + k] : (k < 10) ? u[a * 8 + k - 2] : 0.f;
            a_row[j] = f2bf(v);
        } else if (i < R2) {
            int e = i - R1; int d = s2s_dst[e];
            uint2 p;
            p.x = (unsigned)f2bf(ps[d * 2]) | ((unsigned)f2bf(ps[d * 2 + 1]) << 16);
            p.y = (unsigned)f2bf(s2s_dis[e]) | (0x3F80u << 16);   // dis, 1.0
            *(uint2*)&e_pad_s[(size_t)e * 4] = p;
            unsafeAtomicAdd(&deg[d], 1.0f);
        } else {
            int e = i - R2; int d = a2s_dst[e];
            uint2 p;
            p.x = (unsigned)f2bf(ps[d * 2]) | ((unsigned)f2bf(ps[d * 2 + 1]) << 16);
            p.y = (unsigned)f2bf(a2s_dis[e]) | (0x3F80u << 16);
            *(uint2*)&e_pad_a[(size_t)e * 4] = p;
        }
    }
}

// ---------------------------------------------------------------------------
// prep2: u_row[n][224] = [ps(2), h(64), sum_u(64), sum_x*rd(64), x(8), 0..., 1.0@207, 0...]
// ---------------------------------------------------------------------------
__global__ __launch_bounds__(256) void prep2(
    const float* __restrict__ ps, const float* __restrict__ h,
    const float* __restrict__ x,
    const float* __restrict__ su, const float* __restrict__ sx,
    const float* __restrict__ deg, unsigned short* __restrict__ u_row, int NS)
{
    int total = NS * 224;
    for (int i = blockIdx.x * 256 + threadIdx.x; i < total; i += gridDim.x * 256) {
        int n = i / 224, k = i - n * 224;
        float v;
        if (k < 2)        v = ps[n * 2 + k];
        else if (k < 66)  v = h[n * 64 + k - 2];
        else if (k < 130) v = su[n * 64 + k - 66];
        else if (k < 194) v = sx[n * 64 + k - 130] * (1.0f / fmaxf(deg[n], 1.0f));
        else if (k < 202) v = x[n * 8 + k - 194];
        else if (k == 207) v = 1.0f;
        else              v = 0.f;
        u_row[i] = f2bf(v);
    }
}

// ---------------------------------------------------------------------------
// s2s: K=96 [s_row(80) | psd,dis,1.0,0...], 32 edges/wave, scatter sum_x.
// ---------------------------------------------------------------------------
__global__ __launch_bounds__(256) void s2s_mfma(
    const unsigned short* __restrict__ s_row, const unsigned short* __restrict__ e_pad,
    const int* __restrict__ src, const int* __restrict__ dst,
    const float* __restrict__ w1, const float* __restrict__ b1,
    const float* __restrict__ w2, const float* __restrict__ b2,
    const float* __restrict__ w3, const float* __restrict__ b3,
    float* __restrict__ sum_x, int E)
{
    __shared__ __align__(16) unsigned short B1[3 * 4 * 64 * 8];
    __shared__ __align__(16) unsigned short B2[2 * 4 * 64 * 8];
    __shared__ __align__(16) unsigned short B3[2 * 4 * 64 * 8];
    __shared__ __align__(16) unsigned short Z[4][1024];

    int tid = threadIdx.x;
    build_frags(w1, b1, B1, 3, tid, [](int k) -> int {
        if (k < 2)   return k;          // ps_src
        if (k < 74)  return k + 3;      // x (orig 5..12), h (orig 13..76)
        if (k < 80)  return -2;
        if (k < 82)  return k - 78;     // ps_dst (orig 2,3)
        if (k == 82) return 4;          // dis
        if (k == 83) return -1;         // bias row (x 1.0)
        return -2; });
    build_frags(w2, b2, B2, 2, tid, [](int k) -> int { return k < 64 ? k : -2; });
    build_frags(w3, b3, B3, 2, tid, [](int k) -> int { return k < 64 ? k : -2; });
    __syncthreads();

    int wid = tid >> 6, lane = tid & 63, m16 = lane & 15, q = lane >> 4;
    unsigned short* Zw = Z[wid];

    unsigned int onesd = (q == 0) ? 0x3F80u : 0u;
    FU onesf; onesf.d[0] = onesd; onesf.d[1] = 0; onesf.d[2] = 0; onesf.d[3] = 0;
    unsigned int b2d[4], b3d[4];
    #pragma unroll
    for (int nt = 0; nt < 4; ++nt) {
        b2d[nt] = (q == 0) ? (unsigned)f2bf(b2[nt * 16 + m16]) : 0u;
        b3d[nt] = (q == 0) ? (unsigned)f2bf(b3[nt * 16 + m16]) : 0u;
    }

    int T = E >> 5;
    for (int t = blockIdx.x * 4 + wid; t < T; t += gridDim.x * 4) {
        int e0 = t * 32;
        int eA = e0 + m16, eB = e0 + 16 + m16;
        int sA = src[eA], sB = src[eB];
        int dA = dst[eA], dB = dst[eB];

        FU Lb[2][3]; uint2 ep[2];
        const unsigned short* rA = s_row + (size_t)sA * 80;
        const unsigned short* rB = s_row + (size_t)sB * 80;
        #pragma unroll
        for (int c = 0; c < 3; ++c) {
            Lb[0][c].v = *(const short8*)(rA + c * 32 + q * 8);
            Lb[1][c].v = *(const short8*)(rB + c * 32 + q * 8);
        }
        ep[0] = *(const uint2*)(e_pad + (size_t)eA * 4);
        ep[1] = *(const uint2*)(e_pad + (size_t)eB * 4);
        #pragma unroll
        for (int mt = 0; mt < 2; ++mt) {            // fix chunk 2: q2=e_pad, q3=0
            FU f = Lb[mt][2];
            f.d[0] = q < 2 ? f.d[0] : (q == 2 ? ep[mt].x : 0u);
            f.d[1] = q < 2 ? f.d[1] : (q == 2 ? ep[mt].y : 0u);
            f.d[2] = q < 2 ? f.d[2] : 0u;
            f.d[3] = q < 2 ? f.d[3] : 0u;
            Lb[mt][2] = f;
        }

        f32x4 acc1[2][4];
        #pragma unroll
        for (int mt = 0; mt < 2; ++mt)
            #pragma unroll
            for (int nt = 0; nt < 4; ++nt) acc1[mt][nt] = (f32x4){0.f, 0.f, 0.f, 0.f};
        #pragma unroll
        for (int c = 0; c < 3; ++c)
            #pragma unroll
            for (int nt = 0; nt < 4; ++nt) {
                short8 wf = *(const short8*)(B1 + ((c * 4 + nt) * 64 + lane) * 8);
                acc1[0][nt] = MFMA(wf, Lb[0][c].v, acc1[0][nt]);
                acc1[1][nt] = MFMA(wf, Lb[1][c].v, acc1[1][nt]);
            }

        #pragma unroll
        for (int mt = 0; mt < 2; ++mt) {
            int d = mt ? dB : dA;
            ZSTORE(Zw, acc1[mt], 0)
            short8 zf0 = *(const short8*)(Zw + lane * 8);
            short8 zf1 = *(const short8*)(Zw + 512 + lane * 8);

            f32x4 a2[4];
            #pragma unroll
            for (int nt = 0; nt < 4; ++nt) {
                a2[nt] = (f32x4){0.f, 0.f, 0.f, 0.f};
                short8 w0 = *(const short8*)(B2 + ((0 * 4 + nt) * 64 + lane) * 8);
                short8 w1f = *(const short8*)(B2 + ((1 * 4 + nt) * 64 + lane) * 8);
                a2[nt] = MFMA(w0, zf0, a2[nt]);
                a2[nt] = MFMA(w1f, zf1, a2[nt]);
                FU bf; bf.d[0] = b2d[nt]; bf.d[1] = 0; bf.d[2] = 0; bf.d[3] = 0;
                a2[nt] = MFMA(bf.v, onesf.v, a2[nt]);
            }

            ZSTORE(Zw, a2, 0)
            zf0 = *(const short8*)(Zw + lane * 8);
            zf1 = *(const short8*)(Zw + 512 + lane * 8);

            f32x4 a3[4];
            #pragma unroll
            for (int nt = 0; nt < 4; ++nt) {
                a3[nt] = (f32x4){0.f, 0.f, 0.f, 0.f};
                short8 w0 = *(const short8*)(B3 + ((0 * 4 + nt) * 64 + lane) * 8);
                short8 w1f = *(const short8*)(B3 + ((1 * 4 + nt) * 64 + lane) * 8);
                a3[nt] = MFMA(w0, zf0, a3[nt]);
                a3[nt] = MFMA(w1f, zf1, a3[nt]);
                FU bf; bf.d[0] = b3d[nt]; bf.d[1] = 0; bf.d[2] = 0; bf.d[3] = 0;
                a3[nt] = MFMA(bf.v, onesf.v, a3[nt]);
            }

            #pragma unroll
            for (int nt = 0; nt < 4; ++nt)
                #pragma unroll
                for (int r = 0; r < 4; ++r)
                    unsafeAtomicAdd(&sum_x[(size_t)d * 64 + nt * 16 + q * 4 + r], a3[nt][r]);
        }
    }
}

// ---------------------------------------------------------------------------
// a2s: K=32 [a_row(16) | psd,dis,1.0,0...], scatter sum_u.
// ---------------------------------------------------------------------------
__global__ __launch_bounds__(256) void a2s_mfma(
    const unsigned short* __restrict__ a_row, const unsigned short* __restrict__ e_pad,
    const int* __restrict__ src, const int* __restrict__ dst,
    const float* __restrict__ w1, const float* __restrict__ b1,
    const float* __restrict__ w2, const float* __restrict__ b2,
    const float* __restrict__ w3, const float* __restrict__ b3,
    float* __restrict__ sum_u, int E)
{
    __shared__ __align__(16) unsigned short B1[1 * 4 * 64 * 8];
    __shared__ __align__(16) unsigned short B2[2 * 4 * 64 * 8];
    __shared__ __align__(16) unsigned short B3[2 * 4 * 64 * 8];
    __shared__ __align__(16) unsigned short Z[4][1024];

    int tid = threadIdx.x;
    build_frags(w1, b1, B1, 1, tid, [](int k) -> int {
        if (k < 2)   return k;          // pa
        if (k < 10)  return k + 3;      // u (orig 5..12)
        if (k < 16)  return -2;
        if (k < 18)  return k - 14;     // ps_dst (orig 2,3)
        if (k == 18) return 4;          // dis
        if (k == 19) return -1;         // bias
        return -2; });
    build_frags(w2, b2, B2, 2, tid, [](int k) -> int { return k < 64 ? k : -2; });
    build_frags(w3, b3, B3, 2, tid, [](int k) -> int { return k < 64 ? k : -2; });
    __syncthreads();

    int wid = tid >> 6, lane = tid & 63, m16 = lane & 15, q = lane >> 4;
    unsigned short* Zw = Z[wid];

    unsigned int onesd = (q == 0) ? 0x3F80u : 0u;
    FU onesf; onesf.d[0] = onesd; onesf.d[1] = 0; onesf.d[2] = 0; onesf.d[3] = 0;
    unsigned int b2d[4], b3d[4];
    #pragma unroll
    for (int nt = 0; nt < 4; ++nt) {
        b2d[nt] = (q == 0) ? (unsigned)f2bf(b2[nt * 16 + m16]) : 0u;
        b3d[nt] = (q == 0) ? (unsigned)f2bf(b3[nt * 16 + m16]) : 0u;
    }

    int T = E >> 5;
    for (int t = blockIdx.x * 4 + wid; t < T; t += gridDim.x * 4) {
        int e0 = t * 32;
        int eA = e0 + m16, eB = e0 + 16 + m16;
        int sA = src[eA], sB = src[eB];
        int dA = dst[eA], dB = dst[eB];

        FU Lb[2]; uint2 ep[2];
        Lb[0].v = *(const short8*)(a_row + (size_t)sA * 16 + q * 8);
        Lb[1].v = *(const short8*)(a_row + (size_t)sB * 16 + q * 8);
        ep[0] = *(const uint2*)(e_pad + (size_t)eA * 4);
        ep[1] = *(const uint2*)(e_pad + (size_t)eB * 4);
        #pragma unroll
        for (int mt = 0; mt < 2; ++mt) {   // q0,1 = a_row; q2 = e_pad; q3 = 0
            FU f = Lb[mt];
            f.d[0] = q < 2 ? f.d[0] : (q == 2 ? ep[mt].x : 0u);
            f.d[1] = q < 2 ? f.d[1] : (q == 2 ? ep[mt].y : 0u);
            f.d[2] = q < 2 ? f.d[2] : 0u;
            f.d[3] = q < 2 ? f.d[3] : 0u;
            Lb[mt] = f;
        }

        f32x4 acc1[2][4];
        #pragma unroll
        for (int mt = 0; mt < 2; ++mt)
            #pragma unroll
            for (int nt = 0; nt < 4; ++nt) acc1[mt][nt] = (f32x4){0.f, 0.f, 0.f, 0.f};
        #pragma unroll
        for (int nt = 0; nt < 4; ++nt) {
            short8 wf = *(const short8*)(B1 + (nt * 64 + lane) * 8);
            acc1[0][nt] = MFMA(wf, Lb[0].v, acc1[0][nt]);
            acc1[1][nt] = MFMA(wf, Lb[1].v, acc1[1][nt]);
        }

        #pragma unroll
        for (int mt = 0; mt < 2; ++mt) {
            int d = mt ? dB : dA;
            ZSTORE(Zw, acc1[mt], 0)
            short8 zf0 = *(const short8*)(Zw + lane * 8);
            short8 zf1 = *(const short8*)(Zw + 512 + lane * 8);

            f32x4 a2[4];
            #pragma unroll
            for (int nt = 0; nt < 4; ++nt) {
                a2[nt] = (f32x4){0.f, 0.f, 0.f, 0.f};
                short8 w0 = *(const short8*)(B2 + ((0 * 4 + nt) * 64 + lane) * 8);
                short8 w1f = *(const short8*)(B2 + ((1 * 4 + nt) * 64 + lane) * 8);
                a2[nt] = MFMA(w0, zf0, a2[nt]);
                a2[nt] = MFMA(w1f, zf1, a2[nt]);
                FU bf; bf.d[0] = b2d[nt]; bf.d[1] = 0; bf.d[2] = 0; bf.d[3] = 0;
                a2[nt] = MFMA(bf.v, onesf.v, a2[nt]);
            }

            ZSTORE(Zw, a2, 0)
            zf0 = *(const short8*)(Zw + lane * 8);
            zf1 = *(const short8*)(Zw + 512 + lane * 8);

            f32x4 a3[4];
            #pragma unroll
            for (int nt = 0; nt < 4; ++nt) {
                a3[nt] = (f32x4){0.f, 0.f, 0.f, 0.f};
                short8 w0 = *(const short8*)(B3 + ((0 * 4 + nt) * 64 + lane) * 8);
                short8 w1f = *(const short8*)(B3 + ((1 * 4 + nt) * 64 + lane) * 8);
                a3[nt] = MFMA(w0, zf0, a3[nt]);
                a3[nt] = MFMA(w1f, zf1, a3[nt]);
                FU bf; bf.d[0] = b3d[nt]; bf.d[1] = 0; bf.d[2] = 0; bf.d[3] = 0;
                a3[nt] = MFMA(bf.v, onesf.v, a3[nt]);
            }

            #pragma unroll
            for (int nt = 0; nt < 4; ++nt)
                #pragma unroll
                for (int r = 0; r < 4; ++r)
                    unsafeAtomicAdd(&sum_u[(size_t)d * 64 + nt * 16 + q * 4 + r], a3[nt][r]);
        }
    }
}

// ---------------------------------------------------------------------------
// upd: K=224 from u_row, 16 nodes/wave, direct store.
// ---------------------------------------------------------------------------
__global__ __launch_bounds__(256) void upd_mfma(
    const unsigned short* __restrict__ u_row,
    const float* __restrict__ w1, const float* __restrict__ b1,
    const float* __restrict__ w2, const float* __restrict__ b2,
    const float* __restrict__ w3, const float* __restrict__ b3,
    float* __restrict__ out, int NS)
{
    __shared__ __align__(16) unsigned short B1[7 * 4 * 64 * 8];
    __shared__ __align__(16) unsigned short B2[2 * 4 * 64 * 8];
    __shared__ __align__(16) unsigned short B3[2 * 4 * 64 * 8];
    __shared__ __align__(16) unsigned short Z[4][1024];

    int tid = threadIdx.x;
    build_frags(w1, b1, B1, 7, tid, [](int k) -> int {
        if (k < 202)  return k;
        if (k == 207) return -1;
        return -2; });
    build_frags(w2, b2, B2, 2, tid, [](int k) -> int { return k < 64 ? k : -2; });
    build_frags(w3, b3, B3, 2, tid, [](int k) -> int { return k < 64 ? k : -2; });
    __syncthreads();

    int wid = tid >> 6, lane = tid & 63, m16 = lane & 15, q = lane >> 4;
    unsigned short* Zw = Z[wid];

    unsigned int onesd = (q == 0) ? 0x3F80u : 0u;
    FU onesf; onesf.d[0] = onesd; onesf.d[1] = 0; onesf.d[2] = 0; onesf.d[3] = 0;
    unsigned int b2d[4], b3d[4];
    #pragma unroll
    for (int nt = 0; nt < 4; ++nt) {
        b2d[nt] = (q == 0) ? (unsigned)f2bf(b2[nt * 16 + m16]) : 0u;
        b3d[nt] = (q == 0) ? (unsigned)f2bf(b3[nt * 16 + m16]) : 0u;
    }

    int T = NS >> 4;
    for (int t = blockIdx.x * 4 + wid; t < T; t += gridDim.x * 4) {
        int n0 = t * 16;
        const unsigned short* row = u_row + (size_t)(n0 + m16) * 224;

        f32x4 acc1[4];
        #pragma unroll
        for (int nt = 0; nt < 4; ++nt) acc1[nt] = (f32x4){0.f, 0.f, 0.f, 0.f};
        #pragma unroll
        for (int c = 0; c < 7; ++c) {
            short8 bfrag = *(const short8*)(row + c * 32 + q * 8);
            #pragma unroll
            for (int nt = 0; nt < 4; ++nt) {
                short8 wf = *(const short8*)(B1 + ((c * 4 + nt) * 64 + lane) * 8);
                acc1[nt] = MFMA(wf, bfrag, acc1[nt]);
            }
        }

        ZSTORE(Zw, acc1, 0)
        short8 zf0 = *(const short8*)(Zw + lane * 8);
        short8 zf1 = *(const short8*)(Zw + 512 + lane * 8);

        f32x4 a2[4];
        #pragma unroll
        for (int nt = 0; nt < 4; ++nt) {
            a2[nt] = (f32x4){0.f, 0.f, 0.f, 0.f};
            short8 w0 = *(const short8*)(B2 + ((0 * 4 + nt) * 64 + lane) * 8);
            short8 w1f = *(const short8*)(B2 + ((1 * 4 + nt) * 64 + lane) * 8);
            a2[nt] = MFMA(w0, zf0, a2[nt]);
            a2[nt] = MFMA(w1f, zf1, a2[nt]);
            FU bf; bf.d[0] = b2d[nt]; bf.d[1] = 0; bf.d[2] = 0; bf.d[3] = 0;
            a2[nt] = MFMA(bf.v, onesf.v, a2[nt]);
        }

        ZSTORE(Zw, a2, 0)
        zf0 = *(const short8*)(Zw + lane * 8);
        zf1 = *(const short8*)(Zw + 512 + lane * 8);

        f32x4 a3[4];
        #pragma unroll
        for (int nt = 0; nt < 4; ++nt) {
            a3[nt] = (f32x4){0.f, 0.f, 0.f, 0.f};
            short8 w0 = *(const short8*)(B3 + ((0 * 4 + nt) * 64 + lane) * 8);
            short8 w1f = *(const short8*)(B3 + ((1 * 4 + nt) * 64 + lane) * 8);
            a3[nt] = MFMA(w0, zf0, a3[nt]);
            a3[nt] = MFMA(w1f, zf1, a3[nt]);
            FU bf; bf.d[0] = b3d[nt]; bf.d[1] = 0; bf.d[2] = 0; bf.d[3] = 0;
            a3[nt] = MFMA(bf.v, onesf.v, a3[nt]);
        }

        #pragma unroll
        for (int nt = 0; nt < 4; ++nt)
            #pragma unroll
            for (int r = 0; r < 4; ++r)
                out[(size_t)(n0 + m16) * 64 + nt * 16 + q * 4 + r] = a3[nt][r];
    }
}

extern "C" void kernel_launch(void* const* d_in, const int* in_sizes, int n_in,
                              void* d_out, int out_size, void* d_ws, size_t ws_size,
                              hipStream_t stream) {
    const float* pos_state  = (const float*)d_in[0];
    const float* pos_action = (const float*)d_in[1];
    const float* h          = (const float*)d_in[2];
    const float* x          = (const float*)d_in[3];
    const float* u          = (const float*)d_in[4];
    const int*   a2s_src    = (const int*)d_in[5];
    const int*   a2s_dst    = (const int*)d_in[6];
    const float* a2s_dis    = (const float*)d_in[7];
    const int*   s2s_src    = (const int*)d_in[8];
    const int*   s2s_dst    = (const int*)d_in[9];
    const float* s2s_dis    = (const float*)d_in[10];
    const float* u2h_w1 = (const float*)d_in[11]; const float* u2h_b1 = (const float*)d_in[12];
    const float* u2h_w2 = (const float*)d_in[13]; const float* u2h_b2 = (const float*)d_in[14];
    const float* u2h_w3 = (const float*)d_in[15]; const float* u2h_b3 = (const float*)d_in[16];
    const float* x2h_w1 = (const float*)d_in[17]; const float* x2h_b1 = (const float*)d_in[18];
    const float* x2h_w2 = (const float*)d_in[19]; const float* x2h_b2 = (const float*)d_in[20];
    const float* x2h_w3 = (const float*)d_in[21]; const float* x2h_b3 = (const float*)d_in[22];
    const float* upd_w1 = (const float*)d_in[23]; const float* upd_b1 = (const float*)d_in[24];
    const float* upd_w2 = (const float*)d_in[25]; const float* upd_b2 = (const float*)d_in[26];
    const float* upd_w3 = (const float*)d_in[27]; const float* upd_b3 = (const float*)d_in[28];

    int NS = in_sizes[0] / 2;
    int NA = in_sizes[1] / 2;
    int EA = in_sizes[5];
    int ES = in_sizes[8];

    float* ws    = (float*)d_ws;
    float* sum_u = ws;
    float* sum_x = sum_u + (size_t)NS * 64;
    float* deg   = sum_x + (size_t)NS * 64;
    unsigned short* arena  = (unsigned short*)(deg + NS + 16);
    unsigned short* s_row  = arena;                               // NS*80
    unsigned short* e_pad_s = s_row + (size_t)NS * 80;            // ES*4
    unsigned short* a_row  = e_pad_s + (size_t)ES * 4;            // NA*16
    unsigned short* e_pad_a = a_row + (size_t)NA * 16;            // EA*4
    unsigned short* u_row  = arena;                               // NS*224 (phase 2, aliases)

    hipMemsetAsync(d_ws, 0, ((size_t)NS * 129 + 16) * sizeof(float), stream);

    prep1<<<2048, 256, 0, stream>>>(pos_state, pos_action, h, x, u,
                                    s2s_dst, s2s_dis, a2s_dst, a2s_dis,
                                    s_row, a_row, e_pad_s, e_pad_a, deg,
                                    NS, NA, ES, EA);
    a2s_mfma<<<1024, 256, 0, stream>>>(a_row, e_pad_a, a2s_src, a2s_dst,
                                       u2h_w1, u2h_b1, u2h_w2, u2h_b2, u2h_w3, u2h_b3,
                                       sum_u, EA);
    s2s_mfma<<<1024, 256, 0, stream>>>(s_row, e_pad_s, s2s_src, s2s_dst,
                                       x2h_w1, x2h_b1, x2h_w2, x2h_b2, x2h_w3, x2h_b3,
                                       sum_x, ES);
    prep2<<<2048, 256, 0, stream>>>(pos_state, h, x, sum_u, sum_x, deg, u_row, NS);
    upd_mfma<<<768, 256, 0, stream>>>(u_row,
                                      upd_w1, upd_b1, upd_w2, upd_b2, upd_w3, upd_b3,
                                      (float*)d_out, NS);
}

// Round 4
// 593.931 us; speedup vs baseline: 2.6161x; 2.6161x over previous
//
#include <hip/hip_runtime.h>
#include <hip/hip_bf16.h>

// R4: MFMA with A=edges, B=weights (coalesced scatter like R2), keeping R3's
// pre-packed bf16 rows + vector gathers + bias-via-MFMA. Inter-layer
// transition uses k-permutation pi(f)=4*(f%16)+(f/16) so the C->A-frag
// transpose is 4x ds_write_b64 + 2x ds_read_b128 per tile-half, bank-optimal
// (row stride 72 elems). Weights for layers 2/3 built with pi^-1 row perm.

typedef __attribute__((ext_vector_type(8))) short short8;
typedef __attribute__((ext_vector_type(4))) float f32x4;

#define MFMA(a, b, c) __builtin_amdgcn_mfma_f32_16x16x32_bf16(a, b, c, 0, 0, 0)

union FU { short8 v; unsigned int d[4]; unsigned short us[8]; };

__device__ __forceinline__ unsigned short f2bf(float f) {
    unsigned u = __float_as_uint(f);
    u += 0x7fffu + ((u >> 16) & 1u);   // RNE (data NaN-free)
    return (unsigned short)(u >> 16);
}
__device__ __forceinline__ unsigned int pack2(float a, float b) {
    return (unsigned int)f2bf(a) | ((unsigned int)f2bf(b) << 16);
}
__device__ __forceinline__ float tanh_fast(float xv) {
    float t = __builtin_amdgcn_exp2f(xv * 2.8853900817779268f); // 2*log2(e)
    return 1.0f - 2.0f * __builtin_amdgcn_rcpf(t + 1.0f);
}

// Build B-operand weight fragments in LDS:
// frag(c,nt): lane holds B[k = c*32 + (lane>>4)*8 + j][n = nt*16 + (lane&15)].
// km(k): >=0 -> w[km(k)*64+n], -1 -> b[n], -2 -> 0.
template <typename KM>
__device__ void build_frags(const float* __restrict__ w, const float* __restrict__ b,
                            unsigned short* dst, int nchunks, int tid, KM km) {
    int total = nchunks * 4 * 64;
    for (int f = tid; f < total; f += 256) {
        int lv = f & 63, nt = (f >> 6) & 3, c = f >> 8;
        int n = nt * 16 + (lv & 15);
        int kb = c * 32 + ((lv >> 4) << 3);
        unsigned short* o = dst + f * 8;
        #pragma unroll
        for (int j = 0; j < 8; ++j) {
            int sk = km(kb + j);
            float v = (sk >= 0) ? w[sk * 64 + n] : (sk == -1 ? b[n] : 0.f);
            o[j] = f2bf(v);
        }
    }
}

// pi^-1 for layer-2/3 weight rows: kpos -> logical feature
#define PERM_KM [](int k) -> int { return (k >> 2) + 16 * (k & 3); }

// C-layout (lane q,m16 holds edge=q*4+r, feat=nt*16+m16) -> Zb[edge][kpos],
// kpos = 4*m16 + nt. One b64 write per r; row stride 72 elems (144 B).
#define ZTRANS(Zw, accv, bb)                                                   \
    _Pragma("unroll")                                                          \
    for (int r = 0; r < 4; ++r) {                                              \
        uint2 pv;                                                              \
        pv.x = pack2(tanh_fast(accv[0][r]), tanh_fast(accv[1][r]));            \
        pv.y = pack2(tanh_fast(accv[2][r]), tanh_fast(accv[3][r]));            \
        *(uint2*)((Zw) + ((q << 2) + r) * 72 + (m16 << 2)) = pv;               \
    }

// ---------------------------------------------------------------------------
// prep1: bf16 row tables + edge pads + degree histogram
// ---------------------------------------------------------------------------
__global__ __launch_bounds__(256) void prep1(
    const float* __restrict__ ps, const float* __restrict__ pa,
    const float* __restrict__ h, const float* __restrict__ x,
    const float* __restrict__ u,
    const int* __restrict__ s2s_dst, const float* __restrict__ s2s_dis,
    const int* __restrict__ a2s_dst, const float* __restrict__ a2s_dis,
    unsigned short* __restrict__ s_row, unsigned short* __restrict__ a_row,
    unsigned short* __restrict__ e_pad_s, unsigned short* __restrict__ e_pad_a,
    float* __restrict__ deg, int NS, int NA, int ES, int EA)
{
    int R0 = NS * 80, R1 = R0 + NA * 16, R2 = R1 + ES, R3 = R2 + EA;
    for (int i = blockIdx.x * 256 + threadIdx.x; i < R3; i += gridDim.x * 256) {
        if (i < R0) {
            int n = i / 80, k = i - n * 80;
            float v = (k < 2) ? ps[n * 2 + k] : (k < 10) ? x[n * 8 + k - 2]
                    : (k < 74) ? h[n * 64 + k - 10] : 0.f;
            s_row[i] = f2bf(v);
        } else if (i < R1) {
            int j = i - R0; int a = j / 16, k = j - a * 16;
            float v = (k < 2) ? pa[a * 2 + k] : (k < 10) ? u[a * 8 + k - 2] : 0.f;
            a_row[j] = f2bf(v);
        } else if (i < R2) {
            int e = i - R1; int d = s2s_dst[e];
            uint2 p;
            p.x = (unsigned)f2bf(ps[d * 2]) | ((unsigned)f2bf(ps[d * 2 + 1]) << 16);
            p.y = (unsigned)f2bf(s2s_dis[e]) | (0x3F80u << 16);   // dis, 1.0
            *(uint2*)&e_pad_s[(size_t)e * 4] = p;
            unsafeAtomicAdd(&deg[d], 1.0f);
        } else {
            int e = i - R2; int d = a2s_dst[e];
            uint2 p;
            p.x = (unsigned)f2bf(ps[d * 2]) | ((unsigned)f2bf(ps[d * 2 + 1]) << 16);
            p.y = (unsigned)f2bf(a2s_dis[e]) | (0x3F80u << 16);
            *(uint2*)&e_pad_a[(size_t)e * 4] = p;
        }
    }
}

// ---------------------------------------------------------------------------
// prep2: u_row[n][224] = [ps(2), h(64), sum_u(64), sum_x*rd(64), x(8), 0..., 1.0@207, 0...]
// ---------------------------------------------------------------------------
__global__ __launch_bounds__(256) void prep2(
    const float* __restrict__ ps, const float* __restrict__ h,
    const float* __restrict__ x,
    const float* __restrict__ su, const float* __restrict__ sx,
    const float* __restrict__ deg, unsigned short* __restrict__ u_row, int NS)
{
    int total = NS * 224;
    for (int i = blockIdx.x * 256 + threadIdx.x; i < total; i += gridDim.x * 256) {
        int n = i / 224, k = i - n * 224;
        float v;
        if (k < 2)        v = ps[n * 2 + k];
        else if (k < 66)  v = h[n * 64 + k - 2];
        else if (k < 130) v = su[n * 64 + k - 66];
        else if (k < 194) v = sx[n * 64 + k - 130] * (1.0f / fmaxf(deg[n], 1.0f));
        else if (k < 202) v = x[n * 8 + k - 194];
        else if (k == 207) v = 1.0f;
        else              v = 0.f;
        u_row[i] = f2bf(v);
    }
}

// ---------------------------------------------------------------------------
// s2s: K=96 [s_row(80) | psd,dis,1.0,0...], 32 edges/wave, coalesced scatter.
// ---------------------------------------------------------------------------
__global__ __launch_bounds__(256) void s2s_mfma(
    const unsigned short* __restrict__ s_row, const unsigned short* __restrict__ e_pad,
    const int* __restrict__ src, const int* __restrict__ dst,
    const float* __restrict__ w1, const float* __restrict__ b1,
    const float* __restrict__ w2, const float* __restrict__ b2,
    const float* __restrict__ w3, const float* __restrict__ b3,
    float* __restrict__ sum_x, int E)
{
    __shared__ __align__(16) unsigned short B1[3 * 4 * 64 * 8];
    __shared__ __align__(16) unsigned short B2[2 * 4 * 64 * 8];
    __shared__ __align__(16) unsigned short B3[2 * 4 * 64 * 8];
    __shared__ __align__(16) unsigned short Z[4][16 * 72];

    int tid = threadIdx.x;
    build_frags(w1, b1, B1, 3, tid, [](int k) -> int {
        if (k < 2)   return k;          // ps_src
        if (k < 74)  return k + 3;      // x (orig 5..12), h (orig 13..76)
        if (k < 80)  return -2;
        if (k < 82)  return k - 78;     // ps_dst (orig 2,3)
        if (k == 82) return 4;          // dis
        if (k == 83) return -1;         // bias row (x 1.0)
        return -2; });
    build_frags(w2, b2, B2, 2, tid, PERM_KM);
    build_frags(w3, b3, B3, 2, tid, PERM_KM);
    __syncthreads();

    int wid = tid >> 6, lane = tid & 63, m16 = lane & 15, q = lane >> 4;
    unsigned short* Zw = Z[wid];

    // ones as A operand (A[m][0]=1): q==0 lane, j==0
    FU onesf; onesf.d[0] = (q == 0) ? 0x3F80u : 0u; onesf.d[1] = 0; onesf.d[2] = 0; onesf.d[3] = 0;
    // bias as B operand (B[0][n]=b[n]): q==0 lane, j==0
    unsigned int b2d[4], b3d[4];
    #pragma unroll
    for (int nt = 0; nt < 4; ++nt) {
        b2d[nt] = (q == 0) ? (unsigned)f2bf(b2[nt * 16 + m16]) : 0u;
        b3d[nt] = (q == 0) ? (unsigned)f2bf(b3[nt * 16 + m16]) : 0u;
    }

    int T = E >> 5;
    for (int t = blockIdx.x * 4 + wid; t < T; t += gridDim.x * 4) {
        int e0 = t * 32;
        int eA = e0 + m16, eB = e0 + 16 + m16;
        int sA = src[eA], sB = src[eB];
        int dsc[2][4];
        #pragma unroll
        for (int mt = 0; mt < 2; ++mt)
            #pragma unroll
            for (int r = 0; r < 4; ++r)
                dsc[mt][r] = dst[e0 + mt * 16 + (q << 2) + r];

        FU Lb[2][3]; uint2 ep[2];
        const unsigned short* rA = s_row + (size_t)sA * 80;
        const unsigned short* rB = s_row + (size_t)sB * 80;
        #pragma unroll
        for (int c = 0; c < 3; ++c) {
            Lb[0][c].v = *(const short8*)(rA + c * 32 + q * 8);
            Lb[1][c].v = *(const short8*)(rB + c * 32 + q * 8);
        }
        ep[0] = *(const uint2*)(e_pad + (size_t)eA * 4);
        ep[1] = *(const uint2*)(e_pad + (size_t)eB * 4);
        #pragma unroll
        for (int mt = 0; mt < 2; ++mt) {            // chunk 2: q2=e_pad, q3=0
            FU f = Lb[mt][2];
            f.d[0] = q < 2 ? f.d[0] : (q == 2 ? ep[mt].x : 0u);
            f.d[1] = q < 2 ? f.d[1] : (q == 2 ? ep[mt].y : 0u);
            f.d[2] = q < 2 ? f.d[2] : 0u;
            f.d[3] = q < 2 ? f.d[3] : 0u;
            Lb[mt][2] = f;
        }

        f32x4 acc1[2][4];
        #pragma unroll
        for (int mt = 0; mt < 2; ++mt)
            #pragma unroll
            for (int nt = 0; nt < 4; ++nt) acc1[mt][nt] = (f32x4){0.f, 0.f, 0.f, 0.f};
        #pragma unroll
        for (int c = 0; c < 3; ++c)
            #pragma unroll
            for (int nt = 0; nt < 4; ++nt) {
                short8 wf = *(const short8*)(B1 + ((c * 4 + nt) * 64 + lane) * 8);
                acc1[0][nt] = MFMA(Lb[0][c].v, wf, acc1[0][nt]);
                acc1[1][nt] = MFMA(Lb[1][c].v, wf, acc1[1][nt]);
            }

        #pragma unroll
        for (int mt = 0; mt < 2; ++mt) {
            ZTRANS(Zw, acc1[mt], 0)
            FU A2[2];
            A2[0].v = *(const short8*)(Zw + m16 * 72 + 0 * 32 + q * 8);
            A2[1].v = *(const short8*)(Zw + m16 * 72 + 1 * 32 + q * 8);

            f32x4 a2[4];
            #pragma unroll
            for (int nt = 0; nt < 4; ++nt) {
                a2[nt] = (f32x4){0.f, 0.f, 0.f, 0.f};
                short8 w0 = *(const short8*)(B2 + ((0 * 4 + nt) * 64 + lane) * 8);
                short8 w1f = *(const short8*)(B2 + ((1 * 4 + nt) * 64 + lane) * 8);
                a2[nt] = MFMA(A2[0].v, w0, a2[nt]);
                a2[nt] = MFMA(A2[1].v, w1f, a2[nt]);
                FU bf; bf.d[0] = b2d[nt]; bf.d[1] = 0; bf.d[2] = 0; bf.d[3] = 0;
                a2[nt] = MFMA(onesf.v, bf.v, a2[nt]);
            }

            ZTRANS(Zw, a2, 0)
            FU A3[2];
            A3[0].v = *(const short8*)(Zw + m16 * 72 + 0 * 32 + q * 8);
            A3[1].v = *(const short8*)(Zw + m16 * 72 + 1 * 32 + q * 8);

            f32x4 a3[4];
            #pragma unroll
            for (int nt = 0; nt < 4; ++nt) {
                a3[nt] = (f32x4){0.f, 0.f, 0.f, 0.f};
                short8 w0 = *(const short8*)(B3 + ((0 * 4 + nt) * 64 + lane) * 8);
                short8 w1f = *(const short8*)(B3 + ((1 * 4 + nt) * 64 + lane) * 8);
                a3[nt] = MFMA(A3[0].v, w0, a3[nt]);
                a3[nt] = MFMA(A3[1].v, w1f, a3[nt]);
                FU bf; bf.d[0] = b3d[nt]; bf.d[1] = 0; bf.d[2] = 0; bf.d[3] = 0;
                a3[nt] = MFMA(onesf.v, bf.v, a3[nt]);
            }

            // scatter: lane holds (edge=q*4+r, feat=nt*16+m16); 16 lanes -> 64B line
            #pragma unroll
            for (int nt = 0; nt < 4; ++nt)
                #pragma unroll
                for (int r = 0; r < 4; ++r)
                    unsafeAtomicAdd(&sum_x[(size_t)dsc[mt][r] * 64 + nt * 16 + m16], a3[nt][r]);
        }
    }
}

// ---------------------------------------------------------------------------
// a2s: K=32 [a_row(16) | psd,dis,1.0,0...], coalesced scatter into sum_u.
// ---------------------------------------------------------------------------
__global__ __launch_bounds__(256) void a2s_mfma(
    const unsigned short* __restrict__ a_row, const unsigned short* __restrict__ e_pad,
    const int* __restrict__ src, const int* __restrict__ dst,
    const float* __restrict__ w1, const float* __restrict__ b1,
    const float* __restrict__ w2, const float* __restrict__ b2,
    const float* __restrict__ w3, const float* __restrict__ b3,
    float* __restrict__ sum_u, int E)
{
    __shared__ __align__(16) unsigned short B1[1 * 4 * 64 * 8];
    __shared__ __align__(16) unsigned short B2[2 * 4 * 64 * 8];
    __shared__ __align__(16) unsigned short B3[2 * 4 * 64 * 8];
    __shared__ __align__(16) unsigned short Z[4][16 * 72];

    int tid = threadIdx.x;
    build_frags(w1, b1, B1, 1, tid, [](int k) -> int {
        if (k < 2)   return k;          // pa
        if (k < 10)  return k + 3;      // u (orig 5..12)
        if (k < 16)  return -2;
        if (k < 18)  return k - 14;     // ps_dst (orig 2,3)
        if (k == 18) return 4;          // dis
        if (k == 19) return -1;         // bias
        return -2; });
    build_frags(w2, b2, B2, 2, tid, PERM_KM);
    build_frags(w3, b3, B3, 2, tid, PERM_KM);
    __syncthreads();

    int wid = tid >> 6, lane = tid & 63, m16 = lane & 15, q = lane >> 4;
    unsigned short* Zw = Z[wid];

    FU onesf; onesf.d[0] = (q == 0) ? 0x3F80u : 0u; onesf.d[1] = 0; onesf.d[2] = 0; onesf.d[3] = 0;
    unsigned int b2d[4], b3d[4];
    #pragma unroll
    for (int nt = 0; nt < 4; ++nt) {
        b2d[nt] = (q == 0) ? (unsigned)f2bf(b2[nt * 16 + m16]) : 0u;
        b3d[nt] = (q == 0) ? (unsigned)f2bf(b3[nt * 16 + m16]) : 0u;
    }

    int T = E >> 5;
    for (int t = blockIdx.x * 4 + wid; t < T; t += gridDim.x * 4) {
        int e0 = t * 32;
        int eA = e0 + m16, eB = e0 + 16 + m16;
        int sA = src[eA], sB = src[eB];
        int dsc[2][4];
        #pragma unroll
        for (int mt = 0; mt < 2; ++mt)
            #pragma unroll
            for (int r = 0; r < 4; ++r)
                dsc[mt][r] = dst[e0 + mt * 16 + (q << 2) + r];

        FU Lb[2]; uint2 ep[2];
        Lb[0].v = *(const short8*)(a_row + (size_t)sA * 16 + q * 8);
        Lb[1].v = *(const short8*)(a_row + (size_t)sB * 16 + q * 8);
        ep[0] = *(const uint2*)(e_pad + (size_t)eA * 4);
        ep[1] = *(const uint2*)(e_pad + (size_t)eB * 4);
        #pragma unroll
        for (int mt = 0; mt < 2; ++mt) {   // q0,1 = a_row; q2 = e_pad; q3 = 0
            FU f = Lb[mt];
            f.d[0] = q < 2 ? f.d[0] : (q == 2 ? ep[mt].x : 0u);
            f.d[1] = q < 2 ? f.d[1] : (q == 2 ? ep[mt].y : 0u);
            f.d[2] = q < 2 ? f.d[2] : 0u;
            f.d[3] = q < 2 ? f.d[3] : 0u;
            Lb[mt] = f;
        }

        f32x4 acc1[2][4];
        #pragma unroll
        for (int mt = 0; mt < 2; ++mt)
            #pragma unroll
            for (int nt = 0; nt < 4; ++nt) acc1[mt][nt] = (f32x4){0.f, 0.f, 0.f, 0.f};
        #pragma unroll
        for (int nt = 0; nt < 4; ++nt) {
            short8 wf = *(const short8*)(B1 + (nt * 64 + lane) * 8);
            acc1[0][nt] = MFMA(Lb[0].v, wf, acc1[0][nt]);
            acc1[1][nt] = MFMA(Lb[1].v, wf, acc1[1][nt]);
        }

        #pragma unroll
        for (int mt = 0; mt < 2; ++mt) {
            ZTRANS(Zw, acc1[mt], 0)
            FU A2[2];
            A2[0].v = *(const short8*)(Zw + m16 * 72 + 0 * 32 + q * 8);
            A2[1].v = *(const short8*)(Zw + m16 * 72 + 1 * 32 + q * 8);

            f32x4 a2[4];
            #pragma unroll
            for (int nt = 0; nt < 4; ++nt) {
                a2[nt] = (f32x4){0.f, 0.f, 0.f, 0.f};
                short8 w0 = *(const short8*)(B2 + ((0 * 4 + nt) * 64 + lane) * 8);
                short8 w1f = *(const short8*)(B2 + ((1 * 4 + nt) * 64 + lane) * 8);
                a2[nt] = MFMA(A2[0].v, w0, a2[nt]);
                a2[nt] = MFMA(A2[1].v, w1f, a2[nt]);
                FU bf; bf.d[0] = b2d[nt]; bf.d[1] = 0; bf.d[2] = 0; bf.d[3] = 0;
                a2[nt] = MFMA(onesf.v, bf.v, a2[nt]);
            }

            ZTRANS(Zw, a2, 0)
            FU A3[2];
            A3[0].v = *(const short8*)(Zw + m16 * 72 + 0 * 32 + q * 8);
            A3[1].v = *(const short8*)(Zw + m16 * 72 + 1 * 32 + q * 8);

            f32x4 a3[4];
            #pragma unroll
            for (int nt = 0; nt < 4; ++nt) {
                a3[nt] = (f32x4){0.f, 0.f, 0.f, 0.f};
                short8 w0 = *(const short8*)(B3 + ((0 * 4 + nt) * 64 + lane) * 8);
                short8 w1f = *(const short8*)(B3 + ((1 * 4 + nt) * 64 + lane) * 8);
                a3[nt] = MFMA(A3[0].v, w0, a3[nt]);
                a3[nt] = MFMA(A3[1].v, w1f, a3[nt]);
                FU bf; bf.d[0] = b3d[nt]; bf.d[1] = 0; bf.d[2] = 0; bf.d[3] = 0;
                a3[nt] = MFMA(onesf.v, bf.v, a3[nt]);
            }

            #pragma unroll
            for (int nt = 0; nt < 4; ++nt)
                #pragma unroll
                for (int r = 0; r < 4; ++r)
                    unsafeAtomicAdd(&sum_u[(size_t)dsc[mt][r] * 64 + nt * 16 + m16], a3[nt][r]);
        }
    }
}

// ---------------------------------------------------------------------------
// upd: K=224 from u_row, 16 nodes/wave, row-contiguous store.
// ---------------------------------------------------------------------------
__global__ __launch_bounds__(256) void upd_mfma(
    const unsigned short* __restrict__ u_row,
    const float* __restrict__ w1, const float* __restrict__ b1,
    const float* __restrict__ w2, const float* __restrict__ b2,
    const float* __restrict__ w3, const float* __restrict__ b3,
    float* __restrict__ out, int NS)
{
    __shared__ __align__(16) unsigned short B1[7 * 4 * 64 * 8];
    __shared__ __align__(16) unsigned short B2[2 * 4 * 64 * 8];
    __shared__ __align__(16) unsigned short B3[2 * 4 * 64 * 8];
    __shared__ __align__(16) unsigned short Z[4][16 * 72];

    int tid = threadIdx.x;
    build_frags(w1, b1, B1, 7, tid, [](int k) -> int {
        if (k < 202)  return k;
        if (k == 207) return -1;
        return -2; });
    build_frags(w2, b2, B2, 2, tid, PERM_KM);
    build_frags(w3, b3, B3, 2, tid, PERM_KM);
    __syncthreads();

    int wid = tid >> 6, lane = tid & 63, m16 = lane & 15, q = lane >> 4;
    unsigned short* Zw = Z[wid];

    FU onesf; onesf.d[0] = (q == 0) ? 0x3F80u : 0u; onesf.d[1] = 0; onesf.d[2] = 0; onesf.d[3] = 0;
    unsigned int b2d[4], b3d[4];
    #pragma unroll
    for (int nt = 0; nt < 4; ++nt) {
        b2d[nt] = (q == 0) ? (unsigned)f2bf(b2[nt * 16 + m16]) : 0u;
        b3d[nt] = (q == 0) ? (unsigned)f2bf(b3[nt * 16 + m16]) : 0u;
    }

    int T = NS >> 4;
    for (int t = blockIdx.x * 4 + wid; t < T; t += gridDim.x * 4) {
        int n0 = t * 16;
        const unsigned short* row = u_row + (size_t)(n0 + m16) * 224;

        f32x4 acc1[4];
        #pragma unroll
        for (int nt = 0; nt < 4; ++nt) acc1[nt] = (f32x4){0.f, 0.f, 0.f, 0.f};
        #pragma unroll
        for (int c = 0; c < 7; ++c) {
            short8 afrag = *(const short8*)(row + c * 32 + q * 8);
            #pragma unroll
            for (int nt = 0; nt < 4; ++nt) {
                short8 wf = *(const short8*)(B1 + ((c * 4 + nt) * 64 + lane) * 8);
                acc1[nt] = MFMA(afrag, wf, acc1[nt]);
            }
        }

        ZTRANS(Zw, acc1, 0)
        FU A2[2];
        A2[0].v = *(const short8*)(Zw + m16 * 72 + 0 * 32 + q * 8);
        A2[1].v = *(const short8*)(Zw + m16 * 72 + 1 * 32 + q * 8);

        f32x4 a2[4];
        #pragma unroll
        for (int nt = 0; nt < 4; ++nt) {
            a2[nt] = (f32x4){0.f, 0.f, 0.f, 0.f};
            short8 w0 = *(const short8*)(B2 + ((0 * 4 + nt) * 64 + lane) * 8);
            short8 w1f = *(const short8*)(B2 + ((1 * 4 + nt) * 64 + lane) * 8);
            a2[nt] = MFMA(A2[0].v, w0, a2[nt]);
            a2[nt] = MFMA(A2[1].v, w1f, a2[nt]);
            FU bf; bf.d[0] = b2d[nt]; bf.d[1] = 0; bf.d[2] = 0; bf.d[3] = 0;
            a2[nt] = MFMA(onesf.v, bf.v, a2[nt]);
        }

        ZTRANS(Zw, a2, 0)
        FU A3[2];
        A3[0].v = *(const short8*)(Zw + m16 * 72 + 0 * 32 + q * 8);
        A3[1].v = *(const short8*)(Zw + m16 * 72 + 1 * 32 + q * 8);

        f32x4 a3[4];
        #pragma unroll
        for (int nt = 0; nt < 4; ++nt) {
            a3[nt] = (f32x4){0.f, 0.f, 0.f, 0.f};
            short8 w0 = *(const short8*)(B3 + ((0 * 4 + nt) * 64 + lane) * 8);
            short8 w1f = *(const short8*)(B3 + ((1 * 4 + nt) * 64 + lane) * 8);
            a3[nt] = MFMA(A3[0].v, w0, a3[nt]);
            a3[nt] = MFMA(A3[1].v, w1f, a3[nt]);
            FU bf; bf.d[0] = b3d[nt]; bf.d[1] = 0; bf.d[2] = 0; bf.d[3] = 0;
            a3[nt] = MFMA(onesf.v, bf.v, a3[nt]);
        }

        // store: lane holds (node=q*4+r, feat=nt*16+m16) -> row-contiguous
        #pragma unroll
        for (int nt = 0; nt < 4; ++nt)
            #pragma unroll
            for (int r = 0; r < 4; ++r)
                out[(size_t)(n0 + (q << 2) + r) * 64 + nt * 16 + m16] = a3[nt][r];
    }
}

extern "C" void kernel_launch(void* const* d_in, const int* in_sizes, int n_in,
                              void* d_out, int out_size, void* d_ws, size_t ws_size,
                              hipStream_t stream) {
    const float* pos_state  = (const float*)d_in[0];
    const float* pos_action = (const float*)d_in[1];
    const float* h          = (const float*)d_in[2];
    const float* x          = (const float*)d_in[3];
    const float* u          = (const float*)d_in[4];
    const int*   a2s_src    = (const int*)d_in[5];
    const int*   a2s_dst    = (const int*)d_in[6];
    const float* a2s_dis    = (const float*)d_in[7];
    const int*   s2s_src    = (const int*)d_in[8];
    const int*   s2s_dst    = (const int*)d_in[9];
    const float* s2s_dis    = (const float*)d_in[10];
    const float* u2h_w1 = (const float*)d_in[11]; const float* u2h_b1 = (const float*)d_in[12];
    const float* u2h_w2 = (const float*)d_in[13]; const float* u2h_b2 = (const float*)d_in[14];
    const float* u2h_w3 = (const float*)d_in[15]; const float* u2h_b3 = (const float*)d_in[16];
    const float* x2h_w1 = (const float*)d_in[17]; const float* x2h_b1 = (const float*)d_in[18];
    const float* x2h_w2 = (const float*)d_in[19]; const float* x2h_b2 = (const float*)d_in[20];
    const float* x2h_w3 = (const float*)d_in[21]; const float* x2h_b3 = (const float*)d_in[22];
    const float* upd_w1 = (const float*)d_in[23]; const float* upd_b1 = (const float*)d_in[24];
    const float* upd_w2 = (const float*)d_in[25]; const float* upd_b2 = (const float*)d_in[26];
    const float* upd_w3 = (const float*)d_in[27]; const float* upd_b3 = (const float*)d_in[28];

    int NS = in_sizes[0] / 2;
    int NA = in_sizes[1] / 2;
    int EA = in_sizes[5];
    int ES = in_sizes[8];

    float* ws    = (float*)d_ws;
    float* sum_u = ws;
    float* sum_x = sum_u + (size_t)NS * 64;
    float* deg   = sum_x + (size_t)NS * 64;
    unsigned short* arena  = (unsigned short*)(deg + NS + 16);
    unsigned short* s_row  = arena;                               // NS*80
    unsigned short* e_pad_s = s_row + (size_t)NS * 80;            // ES*4
    unsigned short* a_row  = e_pad_s + (size_t)ES * 4;            // NA*16
    unsigned short* e_pad_a = a_row + (size_t)NA * 16;            // EA*4
    unsigned short* u_row  = arena;                               // NS*224 (phase 2, aliases)

    hipMemsetAsync(d_ws, 0, ((size_t)NS * 129 + 16) * sizeof(float), stream);

    prep1<<<2048, 256, 0, stream>>>(pos_state, pos_action, h, x, u,
                                    s2s_dst, s2s_dis, a2s_dst, a2s_dis,
                                    s_row, a_row, e_pad_s, e_pad_a, deg,
                                    NS, NA, ES, EA);
    a2s_mfma<<<1024, 256, 0, stream>>>(a_row, e_pad_a, a2s_src, a2s_dst,
                                       u2h_w1, u2h_b1, u2h_w2, u2h_b2, u2h_w3, u2h_b3,
                                       sum_u, EA);
    s2s_mfma<<<1024, 256, 0, stream>>>(s_row, e_pad_s, s2s_src, s2s_dst,
                                       x2h_w1, x2h_b1, x2h_w2, x2h_b2, x2h_w3, x2h_b3,
                                       sum_x, ES);
    prep2<<<2048, 256, 0, stream>>>(pos_state, h, x, sum_u, sum_x, deg, u_row, NS);
    upd_mfma<<<768, 256, 0, stream>>>(u_row,
                                      upd_w1, upd_b1, upd_w2, upd_b2, upd_w3, upd_b3,
                                      (float*)d_out, NS);
}